// Round 10
// baseline (254.766 us; speedup 1.0000x reference)
//
#include <hip/hip_runtime.h>
#include <hip/hip_bf16.h>
#include <stdint.h>

#define BATCH 2
#define SEQ   1024
#define DIM   3072
#define KDIM  1024
#define NHEAD 32
#define HDQ   96
#define THR_SIM 0.95f

typedef unsigned short u16;
typedef __attribute__((ext_vector_type(8))) short short8;
typedef __attribute__((ext_vector_type(4))) float f32x4;

typedef const __attribute__((address_space(1))) unsigned int* gas_ptr;
typedef __attribute__((address_space(3))) unsigned int* las_ptr;

__device__ __forceinline__ void glds16(const u16* g, u16* l) {
  __builtin_amdgcn_global_load_lds((gas_ptr)g, (las_ptr)l, 16, 0, 0);
}

__device__ __forceinline__ u16 f2bf(float f) {
  union { float f; unsigned u; } v; v.f = f;
  unsigned r = v.u + 0x7FFFu + ((v.u >> 16) & 1u);
  return (u16)(r >> 16);
}
__device__ __forceinline__ float bf2f(u16 x) {
  union { unsigned u; float f; } v; v.u = ((unsigned)x) << 16; return v.f;
}

__device__ __forceinline__ f32x4 mfma16(short8 a, short8 b, f32x4 c) {
  return __builtin_amdgcn_mfma_f32_16x16x32_bf16(a, b, c, 0, 0, 0);
}

// ---------------- fp32 -> bf16 convert (vectorized) ----------------
__global__ void k_cvt_bf16(const float* __restrict__ in, u16* __restrict__ out, int n4) {
  int i = blockIdx.x * blockDim.x + threadIdx.x;
  if (i < n4) {
    float4 v = ((const float4*)in)[i];
    ushort4 o;
    o.x = f2bf(v.x); o.y = f2bf(v.y); o.z = f2bf(v.z); o.w = f2bf(v.w);
    ((ushort4*)out)[i] = o;
  }
}

// ---------------- transpose fp32 (R,C) -> bf16 (C,R) ----------------
__global__ void k_tr_f32_bf16(const float* __restrict__ in, u16* __restrict__ out, int R, int C) {
  __shared__ float t[32][33];
  int c0 = blockIdx.x * 32, r0 = blockIdx.y * 32;
  int tx = threadIdx.x, ty = threadIdx.y; // (32,8)
  #pragma unroll
  for (int k = 0; k < 4; ++k)
    t[ty + 8 * k][tx] = in[(size_t)(r0 + ty + 8 * k) * C + c0 + tx];
  __syncthreads();
  #pragma unroll
  for (int k = 0; k < 4; ++k)
    out[(size_t)(c0 + ty + 8 * k) * R + r0 + tx] = f2bf(t[tx][ty + 8 * k]);
}

// ---------------- transpose bf16 (R,C) -> (C,R), strided, batched over z ----------------
__global__ void k_tr_bf16(const u16* __restrict__ in, u16* __restrict__ out,
                          int ldin, int ldout, long long zsIn, long long zsOut) {
  __shared__ u16 t[32][33];
  const u16* ib = in + (size_t)blockIdx.z * zsIn;
  u16* ob = out + (size_t)blockIdx.z * zsOut;
  int c0 = blockIdx.x * 32, r0 = blockIdx.y * 32;
  int tx = threadIdx.x, ty = threadIdx.y;
  #pragma unroll
  for (int k = 0; k < 4; ++k)
    t[ty + 8 * k][tx] = ib[(size_t)(r0 + ty + 8 * k) * ldin + c0 + tx];
  __syncthreads();
  #pragma unroll
  for (int k = 0; k < 4; ++k)
    ob[(size_t)(c0 + ty + 8 * k) * ldout + r0 + tx] = t[tx][ty + 8 * k];
}

// ---------------- build extended Wqk operand, pre-scaled by (1/32)*log2(e) ----------------
// rows 0..95 = Wqk*c, row 96 = bqk*c, 97..127 = 0.  Attention then uses
// P = exp2(dot + bias) with NO per-element scale mul (softmax is shift/scale-consistent
// in the exp2 domain; identical math, fewer VALU ops).
__global__ void k_build_wqke(const float* __restrict__ Wqk, const float* __restrict__ bqk,
                             u16* __restrict__ out) {
  const int n = blockIdx.x;           // 0..127
  const int c = threadIdx.x * 4;      // 256 threads x 4
  const float sc = 0.03125f * 1.44269504f;
  float4 v;
  if (n < 96)       v = *(const float4*)(Wqk + (size_t)n * KDIM + c);
  else if (n == 96) v = *(const float4*)(bqk + c);
  else              v = make_float4(0.f, 0.f, 0.f, 0.f);
  ushort4 o;
  o.x = f2bf(v.x * sc); o.y = f2bf(v.y * sc); o.z = f2bf(v.z * sc); o.w = f2bf(v.w * sc);
  *(ushort4*)(out + (size_t)n * KDIM + c) = o;
}

// ---------------- concat bk|bv ----------------
__global__ void k_bkv(const float* __restrict__ bk, const float* __restrict__ bv,
                      float* __restrict__ out) {
  int i = blockIdx.x * 256 + threadIdx.x;
  if (i < 2048) out[i] = (i < 1024) ? bk[i] : bv[i - 1024];
}

// ---------------- GEMM: C = A(M,K;lda) @ Bt(N,K;ldb)^T (+bias[N]) ----------------
// 128x64 tile, BK=64, 4 waves (2x2, wave-tile 64x32), glds dbuf staging,
// XCD-bijective block swizzle (contiguous tm-major chunk per XCD -> A-panels L2-hot).
// LDS swizzle for 128B row stride: source colblk ^= (lane>>3); read colblk ^= (li&7).
// TRI: gram-only path — grid enumerates ONLY upper-triangle tiles (M=1024,N=1024:
// tm in [0,8), tn in [2tm,16), 72 tiles), balanced round-robin (no XCD swizzle).
// batch offsets: off = (zb>>1)*bsH + (zb&1)*bsL for A, B, C.
template<bool OUT_BF16, bool BIAS, bool TRI = false>
__global__ __launch_bounds__(256, 3) void k_gemm_bt(
    const u16* __restrict__ A, const u16* __restrict__ Bt, void* __restrict__ Cv,
    const float* __restrict__ bias, int M, int N, int K,
    int lda, int ldb, int ldc,
    long long bsAH, long long bsAL, long long bsBH, long long bsBL,
    long long bsCH, long long bsCL)
{
  const int zb = blockIdx.y, zH = zb >> 1, zL = zb & 1;
  A  += (size_t)(zH * bsAH + zL * bsAL);
  Bt += (size_t)(zH * bsBH + zL * bsBL);
  u16*   Cb16 = (u16*)Cv + (size_t)(zH * bsCH + zL * bsCL);
  float* Cf32 = (float*)Cv + (size_t)(zH * bsCH + zL * bsCL);

  __shared__ u16 Ls[2][24 * 512];   // per buf: A 16KB (chunks 0-15) + B 8KB (chunks 16-23)
  const int nt = N >> 6;
  int tm, tn;
  if (TRI) {
    // upper-triangle tile enumeration (survivors: tn >= 2*tm), 72 tiles
    int r = blockIdx.x, tmm = 0;
    while (r >= 16 - 2 * tmm) { r -= 16 - 2 * tmm; ++tmm; }
    tm = tmm; tn = 2 * tmm + r;
  } else {
    // XCD-bijective swizzle (m204): XCD x = bid&7 gets a contiguous logical range
    int bid = blockIdx.x;
    const int nwg = gridDim.x;
    const int qq = nwg >> 3, rr = nwg & 7;
    const int x = bid & 7, pos = bid >> 3;
    bid = (x < rr ? x * (qq + 1) : rr * (qq + 1) + (x - rr) * qq) + pos;
    tm = bid / nt; tn = bid % nt;
  }
  const int tid = threadIdx.x, lane = tid & 63, wid = tid >> 6;
  const int wr = wid >> 1, wc = wid & 1, li = lane & 15, lg = lane >> 4;

  // staging: 24 chunks of 1KB (8 rows x 64 cols bf16); wave w owns chunks w*6..w*6+5.
  // lane l covers row (l>>3), colblk (l&7) of the chunk; source colblk pre-swizzled.
  const int rsub = lane >> 3;
  const int cbe = ((lane & 7) ^ rsub) << 3;   // swizzled source col offset (elems)
  const u16* gp[6];
  int lof[6];
  #pragma unroll
  for (int j = 0; j < 6; ++j) {
    const int ci = wid * 6 + j;
    lof[j] = ci << 9;
    if (ci < 16) gp[j] = A + (size_t)(tm * 128 + ci * 8 + rsub) * lda + cbe;
    else         gp[j] = Bt + (size_t)(tn * 64 + (ci - 16) * 8 + rsub) * ldb + cbe;
  }

  f32x4 acc[4][2];
  #pragma unroll
  for (int a = 0; a < 4; ++a)
    #pragma unroll
    for (int b = 0; b < 2; ++b) acc[a][b] = (f32x4){0.f, 0.f, 0.f, 0.f};

  const int nk = K >> 6;
  #pragma unroll
  for (int j = 0; j < 6; ++j) { glds16(gp[j], Ls[0] + lof[j]); gp[j] += 64; }
  __syncthreads();

  for (int kt = 0; kt < nk; ++kt) {
    const u16* Lc = Ls[kt & 1];
    if (kt + 1 < nk) {
      u16* Ln = Ls[(kt + 1) & 1];
      #pragma unroll
      for (int j = 0; j < 6; ++j) { glds16(gp[j], Ln + lof[j]); gp[j] += 64; }
    }
    short8 af[2][4], bfv[2][2];
    #pragma unroll
    for (int ks = 0; ks < 2; ++ks) {
      const int sw = (((ks * 4 + lg) ^ (li & 7)) << 3);
      #pragma unroll
      for (int mf = 0; mf < 4; ++mf)
        af[ks][mf] = *(const short8*)(Lc + (wr * 64 + mf * 16 + li) * 64 + sw);
      #pragma unroll
      for (int nf = 0; nf < 2; ++nf)
        bfv[ks][nf] = *(const short8*)(Lc + 8192 + (wc * 32 + nf * 16 + li) * 64 + sw);
    }
    #pragma unroll
    for (int ks = 0; ks < 2; ++ks)
      #pragma unroll
      for (int mf = 0; mf < 4; ++mf)
        #pragma unroll
        for (int nf = 0; nf < 2; ++nf)
          acc[mf][nf] = mfma16(af[ks][mf], bfv[ks][nf], acc[mf][nf]);
    __syncthreads();
  }
  #pragma unroll
  for (int mf = 0; mf < 4; ++mf) {
    #pragma unroll
    for (int nf = 0; nf < 2; ++nf) {
      const int col = tn * 64 + wc * 32 + nf * 16 + li;
      const float bb = BIAS ? bias[col] : 0.f;
      #pragma unroll
      for (int j = 0; j < 4; ++j) {
        const int row = tm * 128 + wr * 64 + mf * 16 + lg * 4 + j;
        const float v = acc[mf][nf][j] + bb;
        if (OUT_BF16) Cb16[(size_t)row * ldc + col] = f2bf(v);
        else          Cf32[(size_t)row * ldc + col] = v;
      }
    }
  }
}

// ---------------- token replacement: norms, rowAny (parallel), scan+gather ----------------
// 4 slices: s = b*2 + kv; gram slice s at gram + s*SEQ*SEQ; data row view in kv_bf.
__global__ void k_norms(const float* __restrict__ gram, float* __restrict__ nrm,
                        int* __restrict__ anyCnt) {
  const int s = blockIdx.x, j = threadIdx.x;
  const float* g = gram + (size_t)s * SEQ * SEQ;
  float nj = fmaxf(sqrtf(fmaxf(g[(size_t)j * SEQ + j], 0.f)), 1e-8f);
  nrm[s * SEQ + j] = nj;
  if (j == 0) anyCnt[s] = 0;
}

__global__ void k_rowany(const float* __restrict__ gram, const float* __restrict__ nrm,
                         unsigned char* __restrict__ rowAny, int* __restrict__ anyCnt) {
  const int i = blockIdx.x, s = blockIdx.y, t = threadIdx.x; // 256 threads
  const float* g = gram + (size_t)s * SEQ * SEQ + (size_t)i * SEQ;
  const float* nr = nrm + s * SEQ;
  const float ni = nr[i];
  int any = 0;
  for (int j = i + 1 + t; j < SEQ; j += 256)
    any |= (g[j] > THR_SIM * ni * nr[j]) ? 1 : 0;
  any = __any(any) ? 1 : 0;
  __shared__ int sh[4];
  if ((t & 63) == 0) sh[t >> 6] = any;
  __syncthreads();
  if (t == 0) {
    int a = sh[0] | sh[1] | sh[2] | sh[3];
    rowAny[s * SEQ + i] = (unsigned char)a;
    if (a) atomicAdd(&anyCnt[s], 1);
  }
}

__global__ __launch_bounds__(1024) void k_scan_replace(
    const float* __restrict__ gram, const float* __restrict__ nrmG,
    const unsigned char* __restrict__ rowAnyG, const int* __restrict__ anyCnt,
    u16* __restrict__ kvbase)
{
  const int s = blockIdx.x;
  if (anyCnt[s] == 0) return;  // block-uniform fast path
  const float* g = gram + (size_t)s * SEQ * SEQ;
  // kv layout: [2048 rows (b-major)][2048 cols (k|v)]; slice s = b*2 + kv
  u16* dat = kvbase + (size_t)(s >> 1) * (1024 * 2048) + (size_t)(s & 1) * 1024;
  const int ldr = 2048;
  __shared__ float nrm[SEQ];
  __shared__ unsigned char used[SEQ];
  __shared__ unsigned char rowAny[SEQ];
  __shared__ short rep[SEQ];
  const int j = threadIdx.x;
  nrm[j] = nrmG[s * SEQ + j];
  rowAny[j] = rowAnyG[s * SEQ + j];
  used[j] = 0; rep[j] = (short)j;
  __syncthreads();
  for (int i = 0; i < SEQ - 1; ++i) {
    if (rowAny[i] && !used[i]) {
      const float t = THR_SIM * nrm[i];
      if (j > i && !used[j] && g[(size_t)i * SEQ + j] > t * nrm[j]) {
        used[j] = 1; rep[j] = (short)i;
      }
      __syncthreads();
    }
  }
  __syncthreads();
  const int src = rep[j];
  if (src != j) {
    for (int c = 0; c < KDIM; c += 8)
      *(uint4*)(dat + (size_t)j * ldr + c) = *(const uint4*)(dat + (size_t)src * ldr + c);
  }
}

// ---------------- attention probabilities + head-mean partials (v6) ----------------
// = proven k_attn3 structure (66us, round 6) with exp2-domain scores: KKT pre-scaled
// by (1/32)*log2e so the per-element scale mul and exp's internal log2e mul vanish.
// Max pass, float2 red combine, division all byte-identical to attn3.
// grid 512 = xcd(8: b x pg) x 64 q-tiles of 16 rows; 1024 threads = 16 waves,
// wave w owns keys [w*64,+64); KKT frags register-cached across heads.
__global__ __launch_bounds__(1024, 4) void k_attn6(
    const u16* __restrict__ q_bf, const u16* __restrict__ KKTe,
    u16* __restrict__ pbarP)
{
  const int bid = blockIdx.x;
  const int xcd = bid & 7, qt = bid >> 3;
  const int b = xcd >> 2, pg = xcd & 3;
  const int q0 = qt * 16;
  const int tid = threadIdx.x, lane = tid & 63, w = tid >> 6;
  const int li = lane & 15, lg = lane >> 4;

  __shared__ float bkkl[1024];
  __shared__ float2 red[2][16][16];

  const u16* KKb = KKTe + (size_t)b * SEQ * 128;
  bkkl[tid] = bf2f(KKb[(size_t)tid * 128 + 96]);

  short8 ak[4][3];
  #pragma unroll
  for (int kf = 0; kf < 4; ++kf)
    #pragma unroll
    for (int ks = 0; ks < 3; ++ks)
      ak[kf][ks] = *(const short8*)(KKb + (size_t)(w * 64 + kf * 16 + li) * 128 + ks * 32 + lg * 8);

  f32x4 accm[4];
  #pragma unroll
  for (int kf = 0; kf < 4; ++kf) accm[kf] = (f32x4){0.f, 0.f, 0.f, 0.f};
  __syncthreads();

  const u16* qrow = q_bf + (size_t)(b * SEQ + q0 + li) * DIM + pg * 8 * HDQ;

  for (int hh = 0; hh < 8; ++hh) {
    const u16* qp = qrow + hh * HDQ;
    f32x4 acc[4];
    #pragma unroll
    for (int kf = 0; kf < 4; ++kf) acc[kf] = (f32x4){0.f, 0.f, 0.f, 0.f};
    #pragma unroll
    for (int ks = 0; ks < 3; ++ks) {
      short8 bq = *(const short8*)(qp + ks * 32 + lg * 8);
      #pragma unroll
      for (int kf = 0; kf < 4; ++kf)
        acc[kf] = mfma16(ak[kf][ks], bq, acc[kf]);
    }
    // bias (exp2-domain), local max over this wave's 64 keys for q-row li
    float m = -1e30f;
    #pragma unroll
    for (int kf = 0; kf < 4; ++kf) {
      f32x4 bb = *(const f32x4*)(&bkkl[w * 64 + kf * 16 + lg * 4]);
      #pragma unroll
      for (int j = 0; j < 4; ++j) {
        float s = acc[kf][j] + bb[j];
        acc[kf][j] = s;
        m = fmaxf(m, s);
      }
    }
    m = fmaxf(m, __shfl_xor(m, 16));
    m = fmaxf(m, __shfl_xor(m, 32));
    float ssum = 0.f;
    #pragma unroll
    for (int kf = 0; kf < 4; ++kf)
      #pragma unroll
      for (int j = 0; j < 4; ++j) {
        float pv = exp2f(acc[kf][j] - m);
        acc[kf][j] = pv;
        ssum += pv;
      }
    ssum += __shfl_xor(ssum, 16);
    ssum += __shfl_xor(ssum, 32);
    if (lane < 16) red[hh & 1][w][li] = make_float2(m, ssum);
    __syncthreads();
    // combine 16 wave-partials (flash rescale, exp2 domain)
    float mg = -1e30f;
    #pragma unroll
    for (int ww = 0; ww < 16; ++ww) mg = fmaxf(mg, red[hh & 1][ww][li].x);
    float Sg = 0.f;
    #pragma unroll
    for (int ww = 0; ww < 16; ++ww) {
      float2 msv = red[hh & 1][ww][li];
      Sg += msv.y * exp2f(msv.x - mg);
    }
    const float gi = exp2f(m - mg) / (32.f * Sg);
    #pragma unroll
    for (int kf = 0; kf < 4; ++kf)
      #pragma unroll
      for (int j = 0; j < 4; ++j)
        accm[kf][j] += acc[kf][j] * gi;
  }

  u16* dst = pbarP + (size_t)(pg * 2 + b) * SEQ * SEQ + (size_t)(q0 + li) * SEQ + w * 64;
  #pragma unroll
  for (int kf = 0; kf < 4; ++kf) {
    ushort4 o;
    o.x = f2bf(accm[kf][0]); o.y = f2bf(accm[kf][1]);
    o.z = f2bf(accm[kf][2]); o.w = f2bf(accm[kf][3]);
    *(ushort4*)(dst + kf * 16 + lg * 4) = o;
  }
}

// ---------------- reduce 4 Pbar partials -> bf16 Pbar ----------------
__global__ void k_reduce_pbar(const u16* __restrict__ part, u16* __restrict__ out) {
  const size_t N = (size_t)BATCH * SEQ * SEQ;
  size_t i = (size_t)blockIdx.x * blockDim.x + threadIdx.x; // 8-elem chunk
  if (i >= N / 8) return;
  short8 p0 = ((const short8*)part)[i];
  short8 p1 = ((const short8*)(part + N))[i];
  short8 p2 = ((const short8*)(part + 2 * N))[i];
  short8 p3 = ((const short8*)(part + 3 * N))[i];
  short8 o;
  #pragma unroll
  for (int j = 0; j < 8; ++j) {
    float s = bf2f((u16)p0[j]) + bf2f((u16)p1[j]) + bf2f((u16)p2[j]) + bf2f((u16)p3[j]);
    o[j] = (short)f2bf(s);
  }
  ((short8*)out)[i] = o;
}

// ---------------- host ----------------
extern "C" void kernel_launch(void* const* d_in, const int* in_sizes, int n_in,
                              void* d_out, int out_size, void* d_ws, size_t ws_size,
                              hipStream_t stream)
{
  (void)in_sizes; (void)n_in; (void)out_size;
  const float* hs  = (const float*)d_in[0];
  const float* Wq  = (const float*)d_in[1];
  const float* bq  = (const float*)d_in[2];
  const float* Wk  = (const float*)d_in[3];
  const float* bk  = (const float*)d_in[4];
  const float* Wv  = (const float*)d_in[5];
  const float* bv  = (const float*)d_in[6];
  const float* Wqk = (const float*)d_in[7];
  const float* bqk = (const float*)d_in[8];
  const float* Wo  = (const float*)d_in[9];
  const float* bo  = (const float*)d_in[10];

  // workspace layout (sequential lifetimes):
  // [0,12.58M) hs_bf -> gram4 [0,16.78M) (after kv GEMM) -> pbarP [0,16.78M) (after scans)
  // [12.58M,31.46M) WqT -> WkvT [12.58M,25.17M) -> {WqkE,KKTe,vTb,WoT} after kv GEMM
  // [31.46M,44.04M) q_bf ; [44.04M,52.43M) kv_bf -> {Pbar_bf,pv_out}
  // [52.43M,..) smalls
  char* p = (char*)d_ws;
  u16*   hs_bf   = (u16*)(p + 0);
  float* gram4   = (float*)(p + 0);                // 16,777,216 B
  u16*   pbarP   = (u16*)(p + 0);                  // 16,777,216 B
  u16*   WqT     = (u16*)(p + 12582912);           // 18,874,368 B
  u16*   WkvT    = (u16*)(p + 12582912);           // 12,582,912 B
  u16*   WqkE    = (u16*)(p + 16777216);           //    262,144 B
  u16*   KKTe    = (u16*)(p + 17039360);           //    524,288 B
  u16*   vTb     = (u16*)(p + 17563648);           //  4,194,304 B
  u16*   WoT     = (u16*)(p + 21757952);           //  6,291,456 B
  u16*   q_bf    = (u16*)(p + 31457280);           // 12,582,912 B
  u16*   kv_bf   = (u16*)(p + 44040192);           //  8,388,608 B
  u16*   Pbar_bf = (u16*)(p + 44040192);           //  4,194,304 B (after kv dead)
  u16*   pv_out  = (u16*)(p + 48234496);           //  4,194,304 B
  float* bkv     = (float*)(p + 52428800);         //      8,192 B
  float* nrm4    = (float*)(p + 52436992);         //     16,384 B
  unsigned char* rowAny4 = (unsigned char*)(p + 52453376); // 4,096 B
  int*   anyCnt  = (int*)(p + 52457472);           //         16 B
  if (ws_size < 58916864) return;

  const dim3 tb(32, 8);
  const long long SS = (long long)SEQ * SEQ;       // 1,048,576
  const long long KVB = 2048LL * 1024;             // kv batch stride (elems) = 2,097,152

  // hs -> bf16 ; Wq^T ; q = hs @ Wq^T + bq  (grid 16x48 = 768 blocks, 3/CU)
  k_cvt_bf16<<<6144, 256, 0, stream>>>(hs, hs_bf, BATCH * SEQ * DIM / 4);
  k_tr_f32_bf16<<<dim3(96, 96), tb, 0, stream>>>(Wq, WqT, DIM, DIM);
  k_gemm_bt<true, true><<<dim3(768, 1), 256, 0, stream>>>(hs_bf, WqT, q_bf, bq,
      2048, DIM, DIM, DIM, DIM, DIM, 0, 0, 0, 0, 0, 0);
  // WkvT = [Wk^T ; Wv^T] ; bkv ; kv = hs @ WkvT^T + bkv  (grid 16x32 = 512)
  k_tr_f32_bf16<<<dim3(32, 96), tb, 0, stream>>>(Wk, WkvT, DIM, KDIM);
  k_tr_f32_bf16<<<dim3(32, 96), tb, 0, stream>>>(Wv, WkvT + (size_t)1024 * DIM, DIM, KDIM);
  k_bkv<<<8, 256, 0, stream>>>(bk, bv, bkv);
  k_gemm_bt<true, true><<<dim3(512, 1), 256, 0, stream>>>(hs_bf, WkvT, kv_bf, bkv,
      2048, 2048, DIM, DIM, DIM, 2048, 0, 0, 0, 0, 0, 0);
  // gram upper-triangle for all 4 slices (k/v x batch): zb = b*2 + kv  (grid 72x4)
  k_gemm_bt<false, false, true><<<dim3(72, 4), 256, 0, stream>>>(kv_bf, kv_bf, gram4, nullptr,
      SEQ, SEQ, KDIM, 2048, 2048, SEQ,
      KVB, 1024, KVB, 1024, 2 * SS, SS);
  k_norms<<<4, 1024, 0, stream>>>(gram4, nrm4, anyCnt);
  k_rowany<<<dim3(SEQ, 4), 256, 0, stream>>>(gram4, nrm4, rowAny4, anyCnt);
  k_scan_replace<<<4, 1024, 0, stream>>>(gram4, nrm4, rowAny4, anyCnt, kv_bf);
  // KKT = K_new @ [Wqk;bqk;0]^T * (log2e/32) per batch  (grid 16x2)
  k_build_wqke<<<128, 256, 0, stream>>>(Wqk, bqk, WqkE);
  k_gemm_bt<true, false><<<dim3(16, 2), 256, 0, stream>>>(kv_bf, WqkE, KKTe, nullptr,
      SEQ, 128, KDIM, 2048, KDIM, 128, 0, KVB, 0, 0, 0, (long long)SEQ * 128);
  // V^T per batch ; Wo^T
  k_tr_bf16<<<dim3(32, 32, 2), tb, 0, stream>>>(kv_bf + 1024, vTb, 2048, SEQ, KVB, SS);
  k_tr_f32_bf16<<<dim3(96, 32), tb, 0, stream>>>(Wo, WoT, KDIM, DIM);
  // attention probabilities + head-mean partials (no atomics)
  k_attn6<<<512, 1024, 0, stream>>>(q_bf, KKTe, pbarP);
  k_reduce_pbar<<<1024, 256, 0, stream>>>(pbarP, Pbar_bf);
  // pv = Pbar @ V per batch  (grid 128x2 = 256)
  k_gemm_bt<true, false><<<dim3(128, 2), 256, 0, stream>>>(Pbar_bf, vTb, pv_out, nullptr,
      SEQ, KDIM, SEQ, SEQ, SEQ, KDIM, 0, SS, 0, SS, 0, SS);
  // out = pv @ Wo + bo  (grid 16x48 = 768)
  k_gemm_bt<false, true><<<dim3(768, 1), 256, 0, stream>>>(pv_out, WoT, (float*)d_out, bo,
      2048, DIM, KDIM, KDIM, KDIM, DIM, 0, 0, 0, 0, 0, 0);
}

// Round 11
// 249.451 us; speedup vs baseline: 1.0213x; 1.0213x over previous
//
#include <hip/hip_runtime.h>
#include <hip/hip_bf16.h>
#include <stdint.h>

#define BATCH 2
#define SEQ   1024
#define DIM   3072
#define KDIM  1024
#define NHEAD 32
#define HDQ   96
#define THR_SIM 0.95f

typedef unsigned short u16;
typedef __attribute__((ext_vector_type(8))) short short8;
typedef __attribute__((ext_vector_type(4))) float f32x4;

typedef const __attribute__((address_space(1))) unsigned int* gas_ptr;
typedef __attribute__((address_space(3))) unsigned int* las_ptr;

__device__ __forceinline__ void glds16(const u16* g, u16* l) {
  __builtin_amdgcn_global_load_lds((gas_ptr)g, (las_ptr)l, 16, 0, 0);
}

__device__ __forceinline__ u16 f2bf(float f) {
  union { float f; unsigned u; } v; v.f = f;
  unsigned r = v.u + 0x7FFFu + ((v.u >> 16) & 1u);
  return (u16)(r >> 16);
}
__device__ __forceinline__ float bf2f(u16 x) {
  union { unsigned u; float f; } v; v.u = ((unsigned)x) << 16; return v.f;
}

__device__ __forceinline__ f32x4 mfma16(short8 a, short8 b, f32x4 c) {
  return __builtin_amdgcn_mfma_f32_16x16x32_bf16(a, b, c, 0, 0, 0);
}

// ---------------- fp32 -> bf16 convert (vectorized) ----------------
__global__ void k_cvt_bf16(const float* __restrict__ in, u16* __restrict__ out, int n4) {
  int i = blockIdx.x * blockDim.x + threadIdx.x;
  if (i < n4) {
    float4 v = ((const float4*)in)[i];
    ushort4 o;
    o.x = f2bf(v.x); o.y = f2bf(v.y); o.z = f2bf(v.z); o.w = f2bf(v.w);
    ((ushort4*)out)[i] = o;
  }
}

// ---------------- transpose fp32 (R,C) -> bf16 (C,R) ----------------
__global__ void k_tr_f32_bf16(const float* __restrict__ in, u16* __restrict__ out, int R, int C) {
  __shared__ float t[32][33];
  int c0 = blockIdx.x * 32, r0 = blockIdx.y * 32;
  int tx = threadIdx.x, ty = threadIdx.y; // (32,8)
  #pragma unroll
  for (int k = 0; k < 4; ++k)
    t[ty + 8 * k][tx] = in[(size_t)(r0 + ty + 8 * k) * C + c0 + tx];
  __syncthreads();
  #pragma unroll
  for (int k = 0; k < 4; ++k)
    out[(size_t)(c0 + ty + 8 * k) * R + r0 + tx] = f2bf(t[tx][ty + 8 * k]);
}

// ---------------- transpose bf16 (R,C) -> (C,R), strided, batched over z ----------------
__global__ void k_tr_bf16(const u16* __restrict__ in, u16* __restrict__ out,
                          int ldin, int ldout, long long zsIn, long long zsOut) {
  __shared__ u16 t[32][33];
  const u16* ib = in + (size_t)blockIdx.z * zsIn;
  u16* ob = out + (size_t)blockIdx.z * zsOut;
  int c0 = blockIdx.x * 32, r0 = blockIdx.y * 32;
  int tx = threadIdx.x, ty = threadIdx.y;
  #pragma unroll
  for (int k = 0; k < 4; ++k)
    t[ty + 8 * k][tx] = ib[(size_t)(r0 + ty + 8 * k) * ldin + c0 + tx];
  __syncthreads();
  #pragma unroll
  for (int k = 0; k < 4; ++k)
    ob[(size_t)(c0 + ty + 8 * k) * ldout + r0 + tx] = t[tx][ty + 8 * k];
}

// ---------------- build extended Wqk operand: rows 0..95 = Wqk, row 96 = bqk, 97..127 = 0 ----------------
__global__ void k_build_wqke(const float* __restrict__ Wqk, const float* __restrict__ bqk,
                             u16* __restrict__ out) {
  const int n = blockIdx.x;           // 0..127
  const int c = threadIdx.x * 4;      // 256 threads x 4
  float4 v;
  if (n < 96)       v = *(const float4*)(Wqk + (size_t)n * KDIM + c);
  else if (n == 96) v = *(const float4*)(bqk + c);
  else              v = make_float4(0.f, 0.f, 0.f, 0.f);
  ushort4 o;
  o.x = f2bf(v.x); o.y = f2bf(v.y); o.z = f2bf(v.z); o.w = f2bf(v.w);
  *(ushort4*)(out + (size_t)n * KDIM + c) = o;
}

// ---------------- concat bk|bv ----------------
__global__ void k_bkv(const float* __restrict__ bk, const float* __restrict__ bv,
                      float* __restrict__ out) {
  int i = blockIdx.x * 256 + threadIdx.x;
  if (i < 2048) out[i] = (i < 1024) ? bk[i] : bv[i - 1024];
}

// ---------------- GEMM: C = A(M,K;lda) @ Bt(N,K;ldb)^T (+bias[N]) ----------------
// 128x64 tile, BK=64, 4 waves (2x2, wave-tile 64x32), glds dbuf staging,
// XCD-bijective block swizzle (contiguous tm-major chunk per XCD -> A-panels L2-hot).
// LDS swizzle for 128B row stride: source colblk ^= (lane>>3); read colblk ^= (li&7).
// TRI: gram-only path — grid enumerates ONLY upper-triangle tiles (M=1024,N=1024:
// tm in [0,8), tn in [2tm,16), 72 tiles), balanced round-robin (no XCD swizzle).
// batch offsets: off = (zb>>1)*bsH + (zb&1)*bsL for A, B, C.
template<bool OUT_BF16, bool BIAS, bool TRI = false>
__global__ __launch_bounds__(256, 3) void k_gemm_bt(
    const u16* __restrict__ A, const u16* __restrict__ Bt, void* __restrict__ Cv,
    const float* __restrict__ bias, int M, int N, int K,
    int lda, int ldb, int ldc,
    long long bsAH, long long bsAL, long long bsBH, long long bsBL,
    long long bsCH, long long bsCL)
{
  const int zb = blockIdx.y, zH = zb >> 1, zL = zb & 1;
  A  += (size_t)(zH * bsAH + zL * bsAL);
  Bt += (size_t)(zH * bsBH + zL * bsBL);
  u16*   Cb16 = (u16*)Cv + (size_t)(zH * bsCH + zL * bsCL);
  float* Cf32 = (float*)Cv + (size_t)(zH * bsCH + zL * bsCL);

  __shared__ u16 Ls[2][24 * 512];   // per buf: A 16KB (chunks 0-15) + B 8KB (chunks 16-23)
  const int nt = N >> 6;
  int tm, tn;
  if (TRI) {
    // upper-triangle tile enumeration (survivors: tn >= 2*tm), 72 tiles
    int r = blockIdx.x, tmm = 0;
    while (r >= 16 - 2 * tmm) { r -= 16 - 2 * tmm; ++tmm; }
    tm = tmm; tn = 2 * tmm + r;
  } else {
    // XCD-bijective swizzle (m204): XCD x = bid&7 gets a contiguous logical range
    int bid = blockIdx.x;
    const int nwg = gridDim.x;
    const int qq = nwg >> 3, rr = nwg & 7;
    const int x = bid & 7, pos = bid >> 3;
    bid = (x < rr ? x * (qq + 1) : rr * (qq + 1) + (x - rr) * qq) + pos;
    tm = bid / nt; tn = bid % nt;
  }
  const int tid = threadIdx.x, lane = tid & 63, wid = tid >> 6;
  const int wr = wid >> 1, wc = wid & 1, li = lane & 15, lg = lane >> 4;

  // staging: 24 chunks of 1KB (8 rows x 64 cols bf16); wave w owns chunks w*6..w*6+5.
  // lane l covers row (l>>3), colblk (l&7) of the chunk; source colblk pre-swizzled.
  const int rsub = lane >> 3;
  const int cbe = ((lane & 7) ^ rsub) << 3;   // swizzled source col offset (elems)
  const u16* gp[6];
  int lof[6];
  #pragma unroll
  for (int j = 0; j < 6; ++j) {
    const int ci = wid * 6 + j;
    lof[j] = ci << 9;
    if (ci < 16) gp[j] = A + (size_t)(tm * 128 + ci * 8 + rsub) * lda + cbe;
    else         gp[j] = Bt + (size_t)(tn * 64 + (ci - 16) * 8 + rsub) * ldb + cbe;
  }

  f32x4 acc[4][2];
  #pragma unroll
  for (int a = 0; a < 4; ++a)
    #pragma unroll
    for (int b = 0; b < 2; ++b) acc[a][b] = (f32x4){0.f, 0.f, 0.f, 0.f};

  const int nk = K >> 6;
  #pragma unroll
  for (int j = 0; j < 6; ++j) { glds16(gp[j], Ls[0] + lof[j]); gp[j] += 64; }
  __syncthreads();

  for (int kt = 0; kt < nk; ++kt) {
    const u16* Lc = Ls[kt & 1];
    if (kt + 1 < nk) {
      u16* Ln = Ls[(kt + 1) & 1];
      #pragma unroll
      for (int j = 0; j < 6; ++j) { glds16(gp[j], Ln + lof[j]); gp[j] += 64; }
    }
    short8 af[2][4], bfv[2][2];
    #pragma unroll
    for (int ks = 0; ks < 2; ++ks) {
      const int sw = (((ks * 4 + lg) ^ (li & 7)) << 3);
      #pragma unroll
      for (int mf = 0; mf < 4; ++mf)
        af[ks][mf] = *(const short8*)(Lc + (wr * 64 + mf * 16 + li) * 64 + sw);
      #pragma unroll
      for (int nf = 0; nf < 2; ++nf)
        bfv[ks][nf] = *(const short8*)(Lc + 8192 + (wc * 32 + nf * 16 + li) * 64 + sw);
    }
    #pragma unroll
    for (int ks = 0; ks < 2; ++ks)
      #pragma unroll
      for (int mf = 0; mf < 4; ++mf)
        #pragma unroll
        for (int nf = 0; nf < 2; ++nf)
          acc[mf][nf] = mfma16(af[ks][mf], bfv[ks][nf], acc[mf][nf]);
    __syncthreads();
  }
  #pragma unroll
  for (int mf = 0; mf < 4; ++mf) {
    #pragma unroll
    for (int nf = 0; nf < 2; ++nf) {
      const int col = tn * 64 + wc * 32 + nf * 16 + li;
      const float bb = BIAS ? bias[col] : 0.f;
      #pragma unroll
      for (int j = 0; j < 4; ++j) {
        const int row = tm * 128 + wr * 64 + mf * 16 + lg * 4 + j;
        const float v = acc[mf][nf][j] + bb;
        if (OUT_BF16) Cb16[(size_t)row * ldc + col] = f2bf(v);
        else          Cf32[(size_t)row * ldc + col] = v;
      }
    }
  }
}

// ---------------- token replacement: norms, rowAny (parallel), scan+gather ----------------
// 4 slices: s = b*2 + kv; gram slice s at gram + s*SEQ*SEQ; data row view in kv_bf.
__global__ void k_norms(const float* __restrict__ gram, float* __restrict__ nrm,
                        int* __restrict__ anyCnt) {
  const int s = blockIdx.x, j = threadIdx.x;
  const float* g = gram + (size_t)s * SEQ * SEQ;
  float nj = fmaxf(sqrtf(fmaxf(g[(size_t)j * SEQ + j], 0.f)), 1e-8f);
  nrm[s * SEQ + j] = nj;
  if (j == 0) anyCnt[s] = 0;
}

__global__ void k_rowany(const float* __restrict__ gram, const float* __restrict__ nrm,
                         unsigned char* __restrict__ rowAny, int* __restrict__ anyCnt) {
  const int i = blockIdx.x, s = blockIdx.y, t = threadIdx.x; // 256 threads
  const float* g = gram + (size_t)s * SEQ * SEQ + (size_t)i * SEQ;
  const float* nr = nrm + s * SEQ;
  const float ni = nr[i];
  int any = 0;
  for (int j = i + 1 + t; j < SEQ; j += 256)
    any |= (g[j] > THR_SIM * ni * nr[j]) ? 1 : 0;
  any = __any(any) ? 1 : 0;
  __shared__ int sh[4];
  if ((t & 63) == 0) sh[t >> 6] = any;
  __syncthreads();
  if (t == 0) {
    int a = sh[0] | sh[1] | sh[2] | sh[3];
    rowAny[s * SEQ + i] = (unsigned char)a;
    if (a) atomicAdd(&anyCnt[s], 1);
  }
}

__global__ __launch_bounds__(1024) void k_scan_replace(
    const float* __restrict__ gram, const float* __restrict__ nrmG,
    const unsigned char* __restrict__ rowAnyG, const int* __restrict__ anyCnt,
    u16* __restrict__ kvbase)
{
  const int s = blockIdx.x;
  if (anyCnt[s] == 0) return;  // block-uniform fast path
  const float* g = gram + (size_t)s * SEQ * SEQ;
  // kv layout: [2048 rows (b-major)][2048 cols (k|v)]; slice s = b*2 + kv
  u16* dat = kvbase + (size_t)(s >> 1) * (1024 * 2048) + (size_t)(s & 1) * 1024;
  const int ldr = 2048;
  __shared__ float nrm[SEQ];
  __shared__ unsigned char used[SEQ];
  __shared__ unsigned char rowAny[SEQ];
  __shared__ short rep[SEQ];
  const int j = threadIdx.x;
  nrm[j] = nrmG[s * SEQ + j];
  rowAny[j] = rowAnyG[s * SEQ + j];
  used[j] = 0; rep[j] = (short)j;
  __syncthreads();
  for (int i = 0; i < SEQ - 1; ++i) {
    if (rowAny[i] && !used[i]) {
      const float t = THR_SIM * nrm[i];
      if (j > i && !used[j] && g[(size_t)i * SEQ + j] > t * nrm[j]) {
        used[j] = 1; rep[j] = (short)i;
      }
      __syncthreads();
    }
  }
  __syncthreads();
  const int src = rep[j];
  if (src != j) {
    for (int c = 0; c < KDIM; c += 8)
      *(uint4*)(dat + (size_t)j * ldr + c) = *(const uint4*)(dat + (size_t)src * ldr + c);
  }
}

// ---------------- attention probabilities + head-mean partials ----------------
// Swapped-operand MFMA: A = KKT keys (cached in regs across heads), B = q rows.
// grid 512 = xcd(8: b x pg) x 64 q-tiles of 16 rows. 1024 threads = 16 waves,
// wave w owns keys [w*64, w*64+64). One barrier per head (flash combine, 2 LDS slots).
// [proven 66us @ round 6 — byte-identical; attn4/5/6 variants all regressed (codegen)]
__global__ __launch_bounds__(1024, 4) void k_attn3(
    const u16* __restrict__ q_bf, const u16* __restrict__ KKTe,
    u16* __restrict__ pbarP)
{
  const int bid = blockIdx.x;
  const int xcd = bid & 7, qt = bid >> 3;
  const int b = xcd >> 2, pg = xcd & 3;
  const int q0 = qt * 16;
  const int tid = threadIdx.x, lane = tid & 63, w = tid >> 6;
  const int li = lane & 15, lg = lane >> 4;

  __shared__ float bkkl[1024];
  __shared__ float2 red[2][16][16];

  const u16* KKb = KKTe + (size_t)b * SEQ * 128;
  bkkl[tid] = bf2f(KKb[(size_t)tid * 128 + 96]);

  short8 ak[4][3];
  #pragma unroll
  for (int kf = 0; kf < 4; ++kf)
    #pragma unroll
    for (int ks = 0; ks < 3; ++ks)
      ak[kf][ks] = *(const short8*)(KKb + (size_t)(w * 64 + kf * 16 + li) * 128 + ks * 32 + lg * 8);

  f32x4 accm[4];
  #pragma unroll
  for (int kf = 0; kf < 4; ++kf) accm[kf] = (f32x4){0.f, 0.f, 0.f, 0.f};
  __syncthreads();

  const u16* qrow = q_bf + (size_t)(b * SEQ + q0 + li) * DIM + pg * 8 * HDQ;

  for (int hh = 0; hh < 8; ++hh) {
    const u16* qp = qrow + hh * HDQ;
    f32x4 acc[4];
    #pragma unroll
    for (int kf = 0; kf < 4; ++kf) acc[kf] = (f32x4){0.f, 0.f, 0.f, 0.f};
    #pragma unroll
    for (int ks = 0; ks < 3; ++ks) {
      short8 bq = *(const short8*)(qp + ks * 32 + lg * 8);
      #pragma unroll
      for (int kf = 0; kf < 4; ++kf)
        acc[kf] = mfma16(ak[kf][ks], bq, acc[kf]);
    }
    // bias + scale, local max over this wave's 64 keys for q-row li
    float m = -1e30f;
    #pragma unroll
    for (int kf = 0; kf < 4; ++kf) {
      f32x4 bb = *(const f32x4*)(&bkkl[w * 64 + kf * 16 + lg * 4]);
      #pragma unroll
      for (int j = 0; j < 4; ++j) {
        float s = (acc[kf][j] + bb[j]) * 0.03125f;
        acc[kf][j] = s;
        m = fmaxf(m, s);
      }
    }
    m = fmaxf(m, __shfl_xor(m, 16));
    m = fmaxf(m, __shfl_xor(m, 32));
    float ssum = 0.f;
    #pragma unroll
    for (int kf = 0; kf < 4; ++kf)
      #pragma unroll
      for (int j = 0; j < 4; ++j) {
        float pv = __expf(acc[kf][j] - m);
        acc[kf][j] = pv;
        ssum += pv;
      }
    ssum += __shfl_xor(ssum, 16);
    ssum += __shfl_xor(ssum, 32);
    if (lane < 16) red[hh & 1][w][li] = make_float2(m, ssum);
    __syncthreads();
    // combine 16 wave-partials (flash rescale)
    float mg = -1e30f;
    #pragma unroll
    for (int ww = 0; ww < 16; ++ww) mg = fmaxf(mg, red[hh & 1][ww][li].x);
    float Sg = 0.f;
    #pragma unroll
    for (int ww = 0; ww < 16; ++ww) {
      float2 msv = red[hh & 1][ww][li];
      Sg += msv.y * __expf(msv.x - mg);
    }
    const float gi = __expf(m - mg) / (32.f * Sg);
    #pragma unroll
    for (int kf = 0; kf < 4; ++kf)
      #pragma unroll
      for (int j = 0; j < 4; ++j)
        accm[kf][j] += acc[kf][j] * gi;
  }

  u16* dst = pbarP + (size_t)(pg * 2 + b) * SEQ * SEQ + (size_t)(q0 + li) * SEQ + w * 64;
  #pragma unroll
  for (int kf = 0; kf < 4; ++kf) {
    ushort4 o;
    o.x = f2bf(accm[kf][0]); o.y = f2bf(accm[kf][1]);
    o.z = f2bf(accm[kf][2]); o.w = f2bf(accm[kf][3]);
    *(ushort4*)(dst + kf * 16 + lg * 4) = o;
  }
}

// ---------------- reduce 4 Pbar partials -> bf16 Pbar ----------------
__global__ void k_reduce_pbar(const u16* __restrict__ part, u16* __restrict__ out) {
  const size_t N = (size_t)BATCH * SEQ * SEQ;
  size_t i = (size_t)blockIdx.x * blockDim.x + threadIdx.x; // 8-elem chunk
  if (i >= N / 8) return;
  short8 p0 = ((const short8*)part)[i];
  short8 p1 = ((const short8*)(part + N))[i];
  short8 p2 = ((const short8*)(part + 2 * N))[i];
  short8 p3 = ((const short8*)(part + 3 * N))[i];
  short8 o;
  #pragma unroll
  for (int j = 0; j < 8; ++j) {
    float s = bf2f((u16)p0[j]) + bf2f((u16)p1[j]) + bf2f((u16)p2[j]) + bf2f((u16)p3[j]);
    o[j] = (short)f2bf(s);
  }
  ((short8*)out)[i] = o;
}

// ---------------- host ----------------
extern "C" void kernel_launch(void* const* d_in, const int* in_sizes, int n_in,
                              void* d_out, int out_size, void* d_ws, size_t ws_size,
                              hipStream_t stream)
{
  (void)in_sizes; (void)n_in; (void)out_size;
  const float* hs  = (const float*)d_in[0];
  const float* Wq  = (const float*)d_in[1];
  const float* bq  = (const float*)d_in[2];
  const float* Wk  = (const float*)d_in[3];
  const float* bk  = (const float*)d_in[4];
  const float* Wv  = (const float*)d_in[5];
  const float* bv  = (const float*)d_in[6];
  const float* Wqk = (const float*)d_in[7];
  const float* bqk = (const float*)d_in[8];
  const float* Wo  = (const float*)d_in[9];
  const float* bo  = (const float*)d_in[10];

  // workspace layout (sequential lifetimes):
  // [0,12.58M) hs_bf -> gram4 [0,16.78M) (after kv GEMM) -> pbarP [0,16.78M) (after scans)
  // [12.58M,31.46M) WqT -> WkvT [12.58M,25.17M) -> {WqkE,KKTe,vTb,WoT} after kv GEMM
  // [31.46M,44.04M) q_bf ; [44.04M,52.43M) kv_bf -> {Pbar_bf,pv_out}
  // [52.43M,..) smalls
  char* p = (char*)d_ws;
  u16*   hs_bf   = (u16*)(p + 0);
  float* gram4   = (float*)(p + 0);                // 16,777,216 B
  u16*   pbarP   = (u16*)(p + 0);                  // 16,777,216 B
  u16*   WqT     = (u16*)(p + 12582912);           // 18,874,368 B
  u16*   WkvT    = (u16*)(p + 12582912);           // 12,582,912 B
  u16*   WqkE    = (u16*)(p + 16777216);           //    262,144 B
  u16*   KKTe    = (u16*)(p + 17039360);           //    524,288 B
  u16*   vTb     = (u16*)(p + 17563648);           //  4,194,304 B
  u16*   WoT     = (u16*)(p + 21757952);           //  6,291,456 B
  u16*   q_bf    = (u16*)(p + 31457280);           // 12,582,912 B
  u16*   kv_bf   = (u16*)(p + 44040192);           //  8,388,608 B
  u16*   Pbar_bf = (u16*)(p + 44040192);           //  4,194,304 B (after kv dead)
  u16*   pv_out  = (u16*)(p + 48234496);           //  4,194,304 B
  float* bkv     = (float*)(p + 52428800);         //      8,192 B
  float* nrm4    = (float*)(p + 52436992);         //     16,384 B
  unsigned char* rowAny4 = (unsigned char*)(p + 52453376); // 4,096 B
  int*   anyCnt  = (int*)(p + 52457472);           //         16 B
  if (ws_size < 58916864) return;

  const dim3 tb(32, 8);
  const long long SS = (long long)SEQ * SEQ;       // 1,048,576
  const long long KVB = 2048LL * 1024;             // kv batch stride (elems) = 2,097,152

  // hs -> bf16 ; Wq^T ; q = hs @ Wq^T + bq  (grid 16x48 = 768 blocks, 3/CU)
  k_cvt_bf16<<<6144, 256, 0, stream>>>(hs, hs_bf, BATCH * SEQ * DIM / 4);
  k_tr_f32_bf16<<<dim3(96, 96), tb, 0, stream>>>(Wq, WqT, DIM, DIM);
  k_gemm_bt<true, true><<<dim3(768, 1), 256, 0, stream>>>(hs_bf, WqT, q_bf, bq,
      2048, DIM, DIM, DIM, DIM, DIM, 0, 0, 0, 0, 0, 0);
  // WkvT = [Wk^T ; Wv^T] ; bkv ; kv = hs @ WkvT^T + bkv  (grid 16x32 = 512)
  k_tr_f32_bf16<<<dim3(32, 96), tb, 0, stream>>>(Wk, WkvT, DIM, KDIM);
  k_tr_f32_bf16<<<dim3(32, 96), tb, 0, stream>>>(Wv, WkvT + (size_t)1024 * DIM, DIM, KDIM);
  k_bkv<<<8, 256, 0, stream>>>(bk, bv, bkv);
  k_gemm_bt<true, true><<<dim3(512, 1), 256, 0, stream>>>(hs_bf, WkvT, kv_bf, bkv,
      2048, 2048, DIM, DIM, DIM, 2048, 0, 0, 0, 0, 0, 0);
  // gram upper-triangle for all 4 slices (k/v x batch): zb = b*2 + kv  (grid 72x4)
  k_gemm_bt<false, false, true><<<dim3(72, 4), 256, 0, stream>>>(kv_bf, kv_bf, gram4, nullptr,
      SEQ, SEQ, KDIM, 2048, 2048, SEQ,
      KVB, 1024, KVB, 1024, 2 * SS, SS);
  k_norms<<<4, 1024, 0, stream>>>(gram4, nrm4, anyCnt);
  k_rowany<<<dim3(SEQ, 4), 256, 0, stream>>>(gram4, nrm4, rowAny4, anyCnt);
  k_scan_replace<<<4, 1024, 0, stream>>>(gram4, nrm4, rowAny4, anyCnt, kv_bf);
  // KKT = K_new @ [Wqk;bqk;0]^T per batch  (grid 16x2)
  k_build_wqke<<<128, 256, 0, stream>>>(Wqk, bqk, WqkE);
  k_gemm_bt<true, false><<<dim3(16, 2), 256, 0, stream>>>(kv_bf, WqkE, KKTe, nullptr,
      SEQ, 128, KDIM, 2048, KDIM, 128, 0, KVB, 0, 0, 0, (long long)SEQ * 128);
  // V^T per batch ; Wo^T
  k_tr_bf16<<<dim3(32, 32, 2), tb, 0, stream>>>(kv_bf + 1024, vTb, 2048, SEQ, KVB, SS);
  k_tr_f32_bf16<<<dim3(96, 32), tb, 0, stream>>>(Wo, WoT, KDIM, DIM);
  // attention probabilities + head-mean partials (no atomics)
  k_attn3<<<512, 1024, 0, stream>>>(q_bf, KKTe, pbarP);
  k_reduce_pbar<<<1024, 256, 0, stream>>>(pbarP, Pbar_bf);
  // pv = Pbar @ V per batch  (grid 128x2 = 256)
  k_gemm_bt<true, false><<<dim3(128, 2), 256, 0, stream>>>(Pbar_bf, vTb, pv_out, nullptr,
      SEQ, KDIM, SEQ, SEQ, SEQ, KDIM, 0, SS, 0, SS, 0, SS);
  // out = pv @ Wo + bo  (grid 16x48 = 768)
  k_gemm_bt<false, true><<<dim3(768, 1), 256, 0, stream>>>(pv_out, WoT, (float*)d_out, bo,
      2048, DIM, KDIM, KDIM, KDIM, DIM, 0, 0, 0, 0, 0, 0);
}